// Round 1
// 1651.264 us; speedup vs baseline: 1.0607x; 1.0607x over previous
//
#include <hip/hip_runtime.h>
#include <math.h>

typedef unsigned short u16;
typedef unsigned int u32;

using bf16x8 = __attribute__((ext_vector_type(8))) __bf16;
using f32x4  = __attribute__((ext_vector_type(4))) float;

#define SEQ 3072
#define HID 1280
#define NHEADS 16
#define HDIM 80
#define INTER 4608

#define LOG2E 1.44269504088896f
#define M2C   11.5415603f   /* 8 * log2(e) */

__device__ __forceinline__ u16 f2bf(float f) {
    union { float f; u32 u; } v; v.f = f;
    u32 u = v.u;
    u32 r = u + 0x7fffu + ((u >> 16) & 1u);   // round-to-nearest-even
    return (u16)(r >> 16);
}

__device__ __forceinline__ void gld16(const void* g, void* l) {
    __builtin_amdgcn_global_load_lds((const __attribute__((address_space(1))) void*)g,
                                     (__attribute__((address_space(3))) void*)l,
                                     16, 0, 0);
}

// swizzled fragment read: row-major tiles of 8 u16 chunks, chunk c at slot c^(row&7)
__device__ __forceinline__ bf16x8 frag8(const u16* base, int row, int ks, int quad) {
    int c = ks * 4 + quad;
    return *(const bf16x8*)&base[(row * 8 + (c ^ (row & 7))) * 8];
}

// ---------------- transpose + bf16 pack:  W (L,K,N) f32  ->  Wt (L,N,K) bf16
__global__ __launch_bounds__(256) void transpose_pack(const float* __restrict__ src,
                                                      u16* __restrict__ dst, int K, int N) {
    __shared__ float tile[32][33];
    int l = blockIdx.z;
    const float* s = src + (size_t)l * K * N;
    u16* d = dst + (size_t)l * N * K;
    int n0 = blockIdx.x * 32, k0 = blockIdx.y * 32;
    int tx = threadIdx.x & 31, ty = threadIdx.x >> 5;
#pragma unroll
    for (int i = 0; i < 4; i++) {
        int k = ty + i * 8;
        tile[k][tx] = s[(size_t)(k0 + k) * N + n0 + tx];
    }
    __syncthreads();
#pragma unroll
    for (int i = 0; i < 4; i++) {
        int n = ty + i * 8;
        d[(size_t)(n0 + n) * K + k0 + tx] = f2bf(tile[tx][n]);
    }
}

// transpose+pack gate/up into a single interleaved buffer (L, 2N, K):
// real col g, which in {0:gate, 1:up} -> row n2 = ((g>>4)<<5) | (g&15) | (which<<4)
__global__ __launch_bounds__(256) void transpose_pack_gu(const float* __restrict__ src,
                                                         u16* __restrict__ dst, int K, int N,
                                                         int which) {
    __shared__ float tile[32][33];
    int l = blockIdx.z;
    const float* s = src + (size_t)l * K * N;
    u16* d = dst + (size_t)l * (2 * N) * K;
    int n0 = blockIdx.x * 32, k0 = blockIdx.y * 32;
    int tx = threadIdx.x & 31, ty = threadIdx.x >> 5;
#pragma unroll
    for (int i = 0; i < 4; i++) {
        int k = ty + i * 8;
        tile[k][tx] = s[(size_t)(k0 + k) * N + n0 + tx];
    }
    __syncthreads();
#pragma unroll
    for (int i = 0; i < 4; i++) {
        int n = ty + i * 8;
        int g = n0 + n;
        int n2 = ((g >> 4) << 5) | (g & 15) | (which << 4);
        d[(size_t)n2 * K + k0 + tx] = f2bf(tile[tx][n]);
    }
}

// ---------------- layernorm f32 -> bf16 (one row per block)
__global__ __launch_bounds__(256) void ln_kernel(const float* __restrict__ x,
                                                 const float* __restrict__ w,
                                                 const float* __restrict__ b,
                                                 u16* __restrict__ out) {
    int row = blockIdx.x;
    const float* xr = x + (size_t)row * HID;
    float v[5]; float s = 0.f, s2 = 0.f;
#pragma unroll
    for (int i = 0; i < 5; i++) { float t = xr[threadIdx.x + i * 256]; v[i] = t; s += t; s2 += t * t; }
#pragma unroll
    for (int off = 32; off > 0; off >>= 1) { s += __shfl_down(s, off); s2 += __shfl_down(s2, off); }
    __shared__ float red[8];
    int wv = threadIdx.x >> 6;
    if ((threadIdx.x & 63) == 0) { red[wv] = s; red[wv + 4] = s2; }
    __syncthreads();
    s  = red[0] + red[1] + red[2] + red[3];
    s2 = red[4] + red[5] + red[6] + red[7];
    float mu  = s * (1.f / HID);
    float var = s2 * (1.f / HID) - mu * mu;
    float rstd = rsqrtf(var + 1e-6f);
#pragma unroll
    for (int i = 0; i < 5; i++) {
        int col = threadIdx.x + i * 256;
        out[(size_t)row * HID + col] = f2bf((v[i] - mu) * rstd * w[col] + b[col]);
    }
}

// ---------------- qkv pack: fp32 qkv (S,3,16,80) -> rotary + bf16 attention layouts
__global__ __launch_bounds__(256) void qkv_pack(const float* __restrict__ qkv,
                                                const float* __restrict__ rot,
                                                u16* __restrict__ Qp, u16* __restrict__ Kp,
                                                u16* __restrict__ Vt) {
    const float QSC = 0.111803398874989485f * LOG2E;
    int s0 = blockIdx.x * 64, h = blockIdx.y;
    int tid = threadIdx.x;
    __shared__ u16 vlds[80 * 66];
    for (int idx = tid; idx < 64 * 40; idx += 256) {
        int r = idx / 40, d = idx - r * 40;
        const float* base = qkv + (size_t)(s0 + r) * 3840 + h * 80;
        float sn, cs;
        __sincosf(rot[(size_t)(s0 + r) * 40 + d], &sn, &cs);
        float q1 = base[d], q2 = base[d + 40];
        float k1 = base[1280 + d], k2 = base[1280 + d + 40];
        size_t ro = ((size_t)h * SEQ + s0 + r) * 128;
        Qp[ro + d]      = f2bf((q1 * cs - q2 * sn) * QSC);
        Qp[ro + d + 40] = f2bf((q2 * cs + q1 * sn) * QSC);
        Kp[ro + d]      = f2bf(k1 * cs - k2 * sn);
        Kp[ro + d + 40] = f2bf(k2 * cs + k1 * sn);
    }
    for (int idx = tid; idx < 64 * 48; idx += 256) {
        int r = idx / 48, d = 80 + (idx - r * 48);
        size_t ro = ((size_t)h * SEQ + s0 + r) * 128;
        Qp[ro + d] = 0; Kp[ro + d] = 0;
    }
    for (int idx = tid; idx < 64 * 80; idx += 256) {
        int r = idx / 80, d = idx - r * 80;
        vlds[d * 66 + r] = f2bf(qkv[(size_t)(s0 + r) * 3840 + 2560 + h * 80 + d]);
    }
    __syncthreads();
    for (int idx = tid; idx < 80 * 64; idx += 256) {
        int d = idx >> 6, ky = idx & 63;
        Vt[((size_t)h * 80 + d) * SEQ + s0 + ky] = vlds[d * 66 + ky];
    }
}

// ---------------- GEMM v3 (kept for MODE 1: proj / down)
// MODE 1: 128x64 tile,  f32 out + bias + residual
template<int MODE>
__global__ __launch_bounds__(256) void gemm_v3(const u16* __restrict__ A,
                                               const u16* __restrict__ B0,
                                               const u16* __restrict__ B1,
                                               const float* __restrict__ bias0,
                                               const float* __restrict__ bias1,
                                               const float* __restrict__ res,
                                               float* __restrict__ outf,
                                               u16* __restrict__ outh,
                                               int N, int K, int sx, int sy) {
    __shared__ u16 As[8192];
    __shared__ u16 Bs[(MODE == 1) ? 4096 : 8192];
    int tid = threadIdx.x, lane = tid & 63, wave = tid >> 6;
    int quad = lane >> 4, r15 = lane & 15;
    int f = blockIdx.x, xcd = f & 7, j = f >> 3;
    int bx, by;
    if (sx) { bx = xcd * sx + j % sx; by = j / sx; }
    else    { by = xcd * sy + j % sy; bx = j / sy; }
    int mBase = by * 128;
    int nBase = (MODE == 0) ? bx * 128 : bx * 64;

    int rs = tid >> 3, cs = tid & 7;
    int c0 = cs ^ (rs & 7);
    const u16* gA = A + (size_t)(mBase + rs) * K + c0 * 8;
    const u16* gB0 = B0 + (size_t)(nBase + rs) * K + c0 * 8;
    u16* dA = &As[(wave * 64) * 8];

    f32x4 acc[MODE == 0 ? 4 : 2][4] = {};

    int nK = K >> 6;
    for (int kt = 0; kt < nK; kt++) {
        const u16* a = gA + kt * 64;
        const u16* b0 = gB0 + kt * 64;
#pragma unroll
        for (int i = 0; i < 4; i++)
            gld16(a + (size_t)(i * 32) * K, dA + i * 2048);
#pragma unroll
        for (int i = 0; i < 2; i++)
            gld16(b0 + (size_t)(i * 32) * K, &Bs[(wave * 64) * 8 + i * 2048]);
        __syncthreads();

#pragma unroll
        for (int ks = 0; ks < 2; ks++) {
            bf16x8 af[2], bf[4];
#pragma unroll
            for (int mi = 0; mi < 2; mi++) af[mi] = frag8(As, wave * 32 + mi * 16 + r15, ks, quad);
#pragma unroll
            for (int ni = 0; ni < 4; ni++) bf[ni] = frag8(Bs, ni * 16 + r15, ks, quad);
#pragma unroll
            for (int mi = 0; mi < 2; mi++)
#pragma unroll
                for (int ni = 0; ni < 4; ni++)
                    acc[mi][ni] = __builtin_amdgcn_mfma_f32_16x16x32_bf16(af[mi], bf[ni], acc[mi][ni], 0, 0, 0);
        }
        __syncthreads();
    }

#pragma unroll
    for (int ni = 0; ni < 4; ni++) {
        int col = nBase + ni * 16 + r15;
        float bv = bias0[col];
#pragma unroll
        for (int mi = 0; mi < 2; mi++)
#pragma unroll
            for (int jj = 0; jj < 4; jj++) {
                int row = mBase + wave * 32 + mi * 16 + quad * 4 + jj;
                outf[(size_t)row * N + col] = acc[mi][ni][jj] + bv + res[(size_t)row * N + col];
            }
    }
}

// ---------------- GEMM v4: 256x256 tile, 8 waves (2M x 4N), BK=64,
// double-buffered LDS (128 KB), 4-phase/K-tile schedule with raw s_barrier,
// stage of tile t+1 interleaved with compute of tile t, one vmcnt wait per tile.
// EPI 0: f32 out + bias (qkv).  EPI 2: dual interleaved gate/up, silu fuse, bf16 out.
template<int EPI>
__global__ __launch_bounds__(512, 2) void gemm8(const u16* __restrict__ A,
                                                const u16* __restrict__ B,
                                                const float* __restrict__ bias0,
                                                const float* __restrict__ bias1,
                                                float* __restrict__ outf,
                                                u16* __restrict__ outh,
                                                int N, int K) {
    // 2 buffers x (A: 256x64 + B: 256x64) bf16 = 2 x 32768 u16 = 128 KB
    __shared__ u16 sbuf[65536];
    int tid = threadIdx.x, lane = tid & 63, wave = tid >> 6;
    int quad = lane >> 4, r15 = lane & 15;
    int wm = wave >> 2, wn = wave & 3;        // 2 x 4 wave grid; per-wave out 128x64

    // bijective XCD swizzle (m204): contiguous chunk per XCD
    int nwg = gridDim.x;
    int q8 = nwg >> 3, r8 = nwg & 7;
    int xcd = blockIdx.x & 7, j = blockIdx.x >> 3;
    int wg = (xcd < r8 ? xcd * (q8 + 1) : r8 * (q8 + 1) + (xcd - r8) * q8) + j;
    int bx = wg / 12, by = wg % 12;           // M = 3072 -> 12 row tiles
    int mBase = by * 256, nBase = bx * 256;

    // staging descriptors: thread -> (row rs, chunk cs), swizzled source chunk c0
    int rs = tid >> 3, cs = tid & 7;
    int c0 = cs ^ (rs & 7);
    const u16* gA = A + (size_t)(mBase + rs) * K + c0 * 8;
    const u16* gB = B + (size_t)(nBase + rs) * K + c0 * 8;
    int nK = K >> 6;

    f32x4 acc[8][4] = {};

    // stage packet p (16 KB) of K-tile kt into buffer bi.
    // p: 0,1 = A rows {0-127},{128-255}; 2,3 = B rows {0-127},{128-255}
    auto stage = [&](int bi, int kt, int p) {
        const u16* g = (p < 2) ? (gA + (size_t)kt * 64) : (gB + (size_t)kt * 64);
        int i0 = (p & 1) * 2;
        u16* d = &sbuf[bi * 32768 + ((p >= 2) ? 16384 : 0) + wave * 512 + i0 * 4096];
        gld16(g + (size_t)(i0 * 64) * K, d);
        gld16(g + (size_t)((i0 + 1) * 64) * K, d + 4096);
    };

    // prologue: fully stage tile 0 into buffer 0
#pragma unroll
    for (int p = 0; p < 4; p++) stage(0, 0, p);
    asm volatile("s_waitcnt vmcnt(0)" ::: "memory");
    __builtin_amdgcn_s_barrier();

    for (int kt = 0; kt < nK; kt++) {
        int cur = kt & 1;
        const u16* Ab = &sbuf[cur * 32768];
        const u16* Bb = &sbuf[cur * 32768 + 16384];
        bool pre = (kt + 1 < nK);
        bf16x8 bfr[4];
#pragma unroll
        for (int p = 0; p < 4; p++) {
            const int ks = p >> 1, mh = p & 1;
            bf16x8 af[4];
#pragma unroll
            for (int qi = 0; qi < 4; qi++)
                af[qi] = frag8(Ab, wm * 128 + mh * 64 + qi * 16 + r15, ks, quad);
            if ((p & 1) == 0) {
#pragma unroll
                for (int ni = 0; ni < 4; ni++)
                    bfr[ni] = frag8(Bb, wn * 64 + ni * 16 + r15, ks, quad);
            }
            if (pre) stage(cur ^ 1, kt + 1, p);   // uniform branch; writes other buffer
            __builtin_amdgcn_s_barrier();
            __builtin_amdgcn_s_setprio(1);
#pragma unroll
            for (int qi = 0; qi < 4; qi++)
#pragma unroll
                for (int ni = 0; ni < 4; ni++)
                    acc[mh * 4 + qi][ni] = __builtin_amdgcn_mfma_f32_16x16x32_bf16(
                        af[qi], bfr[ni], acc[mh * 4 + qi][ni], 0, 0, 0);
            __builtin_amdgcn_s_setprio(0);
            if (p < 3) __builtin_amdgcn_s_barrier();
        }
        // tile boundary: next tile's 8 staging loads (issued above) must land
        if (pre) { asm volatile("s_waitcnt vmcnt(0)" ::: "memory"); }
        __builtin_amdgcn_s_barrier();
    }

    if constexpr (EPI == 0) {
#pragma unroll
        for (int ni = 0; ni < 4; ni++) {
            int col = nBase + wn * 64 + ni * 16 + r15;
            float bv = bias0[col];
#pragma unroll
            for (int mi = 0; mi < 8; mi++)
#pragma unroll
                for (int jj = 0; jj < 4; jj++) {
                    int row = mBase + wm * 128 + mi * 16 + quad * 4 + jj;
                    outf[(size_t)row * N + col] = acc[mi][ni][jj] + bv;
                }
        }
    } else {
        // interleaved dual: even ni = gate frag, odd ni = up frag (same real cols)
#pragma unroll
        for (int pp = 0; pp < 2; pp++) {
            int col = (nBase >> 1) + wn * 32 + pp * 16 + r15;
            float gb = bias0[col], ub = bias1[col];
#pragma unroll
            for (int mi = 0; mi < 8; mi++)
#pragma unroll
                for (int jj = 0; jj < 4; jj++) {
                    int row = mBase + wm * 128 + mi * 16 + quad * 4 + jj;
                    float g = acc[mi][2 * pp][jj] + gb;
                    float u = acc[mi][2 * pp + 1][jj] + ub;
                    float sg = g / (1.f + __expf(-g));
                    outh[(size_t)row * INTER + col] = f2bf(sg * u);
                }
        }
    }
}

// ---------------- flash attention with sinks v2 (unchanged)
__global__ __launch_bounds__(256) void attn_kernel(const u16* __restrict__ Qp,
                                                   const u16* __restrict__ Kp,
                                                   const u16* __restrict__ Vt,
                                                   const float* __restrict__ s_aux,
                                                   u16* __restrict__ out, int windowed) {
    __shared__ u16 q_lds[8192];
    __shared__ u16 k_lds[8192];
    __shared__ u16 v_lds[5120];
    __shared__ u16 p_lds[64 * 72];

    int qt = blockIdx.x, h = blockIdx.y;
    int tid = threadIdx.x, lane = tid & 63, wave = tid >> 6;
    int quad = lane >> 4, r15 = lane & 15;

    const u16* Qh = Qp + (size_t)h * SEQ * 128;
    const u16* Kh = Kp + (size_t)h * SEQ * 128;
    const u16* Vh = Vt + (size_t)h * 80 * SEQ;

    {
        int q0 = qt * 64;
#pragma unroll
        for (int i = 0; i < 4; i++) {
            int slot = i * 256 + wave * 64 + lane;
            int row = slot >> 4, cc = slot & 15;
            int c = cc ^ (row & 7);
            gld16(Qh + (size_t)(q0 + row) * 128 + c * 8, &q_lds[(i * 256 + wave * 64) * 8]);
        }
    }
    __syncthreads();
    bf16x8 aq[3];
#pragma unroll
    for (int ks = 0; ks < 3; ks++) {
        int row = wave * 16 + r15;
        int c = ks * 4 + quad;
        aq[ks] = *(const bf16x8*)&q_lds[(row * 16 + (c ^ (row & 7))) * 8];
    }

    float l_j[4] = {0.f, 0.f, 0.f, 0.f};
    f32x4 ov[5] = {};

    int nT = windowed ? 1 : (SEQ / 64);
    int tBase = windowed ? qt : 0;
    for (int t = 0; t < nT; t++) {
        int key0 = (tBase + t) * 64;
        __syncthreads();
#pragma unroll
        for (int i = 0; i < 4; i++) {
            int slot = i * 256 + wave * 64 + lane;
            int row = slot >> 4, cc = slot & 15;
            int c = cc ^ (row & 7);
            gld16(Kh + (size_t)(key0 + row) * 128 + c * 8, &k_lds[(i * 256 + wave * 64) * 8]);
        }
#pragma unroll
        for (int i = 0; i < 2; i++) {
            int slot = i * 256 + wave * 64 + lane;
            int row = slot >> 3, cc = slot & 7;
            int c = cc ^ (row & 7);
            gld16(Vh + (size_t)row * SEQ + key0 + c * 8, &v_lds[(i * 256 + wave * 64) * 8]);
        }
        if (wave < 2) {
            int slot = 512 + wave * 64 + lane;
            int row = slot >> 3, cc = slot & 7;
            int c = cc ^ (row & 7);
            gld16(Vh + (size_t)row * SEQ + key0 + c * 8, &v_lds[(512 + wave * 64) * 8]);
        }
        __syncthreads();

        f32x4 sc[4];
#pragma unroll
        for (int nt = 0; nt < 4; nt++) {
            f32x4 z = {};
#pragma unroll
            for (int ks = 0; ks < 3; ks++) {
                int row = nt * 16 + r15;
                int c = ks * 4 + quad;
                bf16x8 bk = *(const bf16x8*)&k_lds[(row * 16 + (c ^ (row & 7))) * 8];
                z = __builtin_amdgcn_mfma_f32_16x16x32_bf16(aq[ks], bk, z, 0, 0, 0);
            }
            sc[nt] = z;
        }
#pragma unroll
        for (int nt = 0; nt < 4; nt++)
#pragma unroll
            for (int jj = 0; jj < 4; jj++) {
                float p = __builtin_amdgcn_exp2f(sc[nt][jj] - M2C);
                l_j[jj] += p;
                p_lds[(wave * 16 + quad * 4 + jj) * 72 + nt * 16 + r15] = f2bf(p);
            }
        asm volatile("s_waitcnt lgkmcnt(0)" ::: "memory");
        bf16x8 ap[2];
#pragma unroll
        for (int ks = 0; ks < 2; ks++)
            ap[ks] = *(const bf16x8*)&p_lds[(wave * 16 + r15) * 72 + ks * 32 + quad * 8];
#pragma unroll
        for (int t5 = 0; t5 < 5; t5++)
#pragma unroll
            for (int ks = 0; ks < 2; ks++) {
                int d = t5 * 16 + r15;
                int c = ks * 4 + quad;
                bf16x8 bv = *(const bf16x8*)&v_lds[(d * 8 + (c ^ (d & 7))) * 8];
                ov[t5] = __builtin_amdgcn_mfma_f32_16x16x32_bf16(ap[ks], bv, ov[t5], 0, 0, 0);
            }
    }
#pragma unroll
    for (int off = 1; off < 16; off <<= 1)
#pragma unroll
        for (int jj = 0; jj < 4; jj++)
            l_j[jj] += __shfl_xor(l_j[jj], off, 64);
    float sink = s_aux[h];
    float se = __builtin_amdgcn_exp2f(sink * LOG2E - M2C);
#pragma unroll
    for (int jj = 0; jj < 4; jj++) l_j[jj] = 1.f / (l_j[jj] + se);
#pragma unroll
    for (int t5 = 0; t5 < 5; t5++)
#pragma unroll
        for (int jj = 0; jj < 4; jj++) {
            int row = qt * 64 + wave * 16 + quad * 4 + jj;
            int d = t5 * 16 + r15;
            out[(size_t)row * HID + h * 80 + d] = f2bf(ov[t5][jj] * l_j[jj]);
        }
}

__global__ __launch_bounds__(256) void copy4_kernel(const float4* __restrict__ src,
                                                    float4* __restrict__ dst) {
    size_t i = (size_t)blockIdx.x * 256 + threadIdx.x;
    dst[i] = src[i];
}

extern "C" void kernel_launch(void* const* d_in, const int* in_sizes, int n_in,
                              void* d_out, int out_size, void* d_ws, size_t ws_size,
                              hipStream_t stream) {
    const float* x      = (const float*)d_in[0];
    const float* rot    = (const float*)d_in[1];
    const float* s_aux  = (const float*)d_in[2];
    const float* ln1_w  = (const float*)d_in[3];
    const float* ln1_b  = (const float*)d_in[4];
    const float* qkv_w  = (const float*)d_in[5];
    const float* qkv_b  = (const float*)d_in[6];
    const float* proj_w = (const float*)d_in[7];
    const float* proj_b = (const float*)d_in[8];
    const float* ln2_w  = (const float*)d_in[9];
    const float* ln2_b  = (const float*)d_in[10];
    const float* gate_w = (const float*)d_in[11];
    const float* gate_b = (const float*)d_in[12];
    const float* up_w   = (const float*)d_in[13];
    const float* up_b   = (const float*)d_in[14];
    const float* down_w = (const float*)d_in[15];
    const float* down_b = (const float*)d_in[16];

    char* ws = (char*)d_ws;
    size_t off = 0;
    auto alloc = [&](size_t n) -> char* {
        char* p = ws + off; off += (n + 255) & ~(size_t)255; return p;
    };
    u16* wt_qkv  = (u16*)alloc((size_t)4 * 3840 * 1280 * 2);
    u16* wt_proj = (u16*)alloc((size_t)4 * 1280 * 1280 * 2);
    u16* wt_gu   = (u16*)alloc((size_t)4 * 9216 * 1280 * 2);   // interleaved gate/up
    u16* wt_down = (u16*)alloc((size_t)4 * 1280 * 4608 * 2);
    float* h     = (float*)alloc((size_t)3072 * 1280 * 4);
    u16*  xn     = (u16*)alloc((size_t)3072 * 1280 * 2);
    float* gbuf  = (float*)alloc((size_t)3072 * 4608 * 4);
    float* qkvb  = gbuf;  // alias: qkv buffer dead before MLP
    u16*  attnb  = (u16*)alloc((size_t)3072 * 1280 * 2);
    float* ubuf  = (float*)alloc((size_t)3072 * 4608 * 4);
    u16*  mbuf   = (u16*)alloc((size_t)3072 * 4608 * 2);
    u16* Qp  = (u16*)ubuf;
    u16* Kp  = Qp + (size_t)NHEADS * SEQ * 128;
    u16* Vtp = Kp + (size_t)NHEADS * SEQ * 128;

    transpose_pack<<<dim3(120, 40, 4), 256, 0, stream>>>(qkv_w,  wt_qkv,  1280, 3840);
    transpose_pack<<<dim3(40,  40, 4), 256, 0, stream>>>(proj_w, wt_proj, 1280, 1280);
    transpose_pack_gu<<<dim3(144, 40, 4), 256, 0, stream>>>(gate_w, wt_gu, 1280, 4608, 0);
    transpose_pack_gu<<<dim3(144, 40, 4), 256, 0, stream>>>(up_w,   wt_gu, 1280, 4608, 1);
    transpose_pack<<<dim3(40, 144, 4), 256, 0, stream>>>(down_w, wt_down, 4608, 1280);

    copy4_kernel<<<3840, 256, 0, stream>>>((const float4*)x, (float4*)h);

    for (int l = 0; l < 4; l++) {
        ln_kernel<<<3072, 256, 0, stream>>>(h, ln1_w + l * 1280, ln1_b + l * 1280, xn);
        gemm8<0><<<180, 512, 0, stream>>>(xn, wt_qkv + (size_t)l * 3840 * 1280,
                                          qkv_b + l * 3840, nullptr, qkvb, nullptr,
                                          3840, 1280);
        qkv_pack<<<dim3(48, 16), 256, 0, stream>>>(qkvb, rot, Qp, Kp, Vtp);
        attn_kernel<<<dim3(48, 16), 256, 0, stream>>>(Qp, Kp, Vtp, s_aux, attnb, (l == 3) ? 0 : 1);
        gemm_v3<1><<<480, 256, 0, stream>>>(attnb, wt_proj + (size_t)l * 1280 * 1280, nullptr,
                                            proj_b + l * 1280, nullptr, h, h, nullptr,
                                            1280, 1280, 0, 3);
        ln_kernel<<<3072, 256, 0, stream>>>(h, ln2_w + l * 1280, ln2_b + l * 1280, xn);
        gemm8<2><<<432, 512, 0, stream>>>(xn, wt_gu + (size_t)l * 9216 * 1280,
                                          gate_b + l * 4608, up_b + l * 4608,
                                          nullptr, mbuf, 9216, 1280);
        float* outp = (l == 3) ? (float*)d_out : h;
        gemm_v3<1><<<480, 256, 0, stream>>>(mbuf, wt_down + (size_t)l * 4608 * 1280, nullptr,
                                            down_b + l * 1280, nullptr, h, outp, nullptr,
                                            1280, 4608, 0, 3);
    }
}

// Round 2
// 1556.906 us; speedup vs baseline: 1.1249x; 1.0606x over previous
//
#include <hip/hip_runtime.h>
#include <math.h>

typedef unsigned short u16;
typedef unsigned int u32;

using bf16x8 = __attribute__((ext_vector_type(8))) __bf16;
using f32x4  = __attribute__((ext_vector_type(4))) float;

#define SEQ 3072
#define HID 1280
#define NHEADS 16
#define HDIM 80
#define INTER 4608

#define LOG2E 1.44269504088896f
#define M2C   11.5415603f   /* 8 * log2(e) */

__device__ __forceinline__ u16 f2bf(float f) {
    __bf16 h = (__bf16)f;               // HW v_cvt, RNE — replaces 5-op manual round
    return __builtin_bit_cast(u16, h);
}

__device__ __forceinline__ void gld16(const void* g, void* l) {
    __builtin_amdgcn_global_load_lds((const __attribute__((address_space(1))) void*)g,
                                     (__attribute__((address_space(3))) void*)l,
                                     16, 0, 0);
}

// swizzled fragment read: row-major tiles of 8 u16 chunks, chunk c at slot c^(row&7)
__device__ __forceinline__ bf16x8 frag8(const u16* base, int row, int ks, int quad) {
    int c = ks * 4 + quad;
    return *(const bf16x8*)&base[(row * 8 + (c ^ (row & 7))) * 8];
}

// ---------------- transpose + bf16 pack:  W (L,K,N) f32  ->  Wt (L,N,K) bf16
__global__ __launch_bounds__(256) void transpose_pack(const float* __restrict__ src,
                                                      u16* __restrict__ dst, int K, int N) {
    __shared__ float tile[32][33];
    int l = blockIdx.z;
    const float* s = src + (size_t)l * K * N;
    u16* d = dst + (size_t)l * N * K;
    int n0 = blockIdx.x * 32, k0 = blockIdx.y * 32;
    int tx = threadIdx.x & 31, ty = threadIdx.x >> 5;
#pragma unroll
    for (int i = 0; i < 4; i++) {
        int k = ty + i * 8;
        tile[k][tx] = s[(size_t)(k0 + k) * N + n0 + tx];
    }
    __syncthreads();
#pragma unroll
    for (int i = 0; i < 4; i++) {
        int n = ty + i * 8;
        d[(size_t)(n0 + n) * K + k0 + tx] = f2bf(tile[tx][n]);
    }
}

// transpose+pack gate/up into a single interleaved buffer (L, 2N, K):
// real col g, which in {0:gate, 1:up} -> row n2 = ((g>>4)<<5) | (g&15) | (which<<4)
__global__ __launch_bounds__(256) void transpose_pack_gu(const float* __restrict__ src,
                                                         u16* __restrict__ dst, int K, int N,
                                                         int which) {
    __shared__ float tile[32][33];
    int l = blockIdx.z;
    const float* s = src + (size_t)l * K * N;
    u16* d = dst + (size_t)l * (2 * N) * K;
    int n0 = blockIdx.x * 32, k0 = blockIdx.y * 32;
    int tx = threadIdx.x & 31, ty = threadIdx.x >> 5;
#pragma unroll
    for (int i = 0; i < 4; i++) {
        int k = ty + i * 8;
        tile[k][tx] = s[(size_t)(k0 + k) * N + n0 + tx];
    }
    __syncthreads();
#pragma unroll
    for (int i = 0; i < 4; i++) {
        int n = ty + i * 8;
        int g = n0 + n;
        int n2 = ((g >> 4) << 5) | (g & 15) | (which << 4);
        d[(size_t)n2 * K + k0 + tx] = f2bf(tile[tx][n]);
    }
}

// ---------------- layernorm f32 -> bf16 (one row per block)
__global__ __launch_bounds__(256) void ln_kernel(const float* __restrict__ x,
                                                 const float* __restrict__ w,
                                                 const float* __restrict__ b,
                                                 u16* __restrict__ out) {
    int row = blockIdx.x;
    const float* xr = x + (size_t)row * HID;
    float v[5]; float s = 0.f, s2 = 0.f;
#pragma unroll
    for (int i = 0; i < 5; i++) { float t = xr[threadIdx.x + i * 256]; v[i] = t; s += t; s2 += t * t; }
#pragma unroll
    for (int off = 32; off > 0; off >>= 1) { s += __shfl_down(s, off); s2 += __shfl_down(s2, off); }
    __shared__ float red[8];
    int wv = threadIdx.x >> 6;
    if ((threadIdx.x & 63) == 0) { red[wv] = s; red[wv + 4] = s2; }
    __syncthreads();
    s  = red[0] + red[1] + red[2] + red[3];
    s2 = red[4] + red[5] + red[6] + red[7];
    float mu  = s * (1.f / HID);
    float var = s2 * (1.f / HID) - mu * mu;
    float rstd = rsqrtf(var + 1e-6f);
#pragma unroll
    for (int i = 0; i < 5; i++) {
        int col = threadIdx.x + i * 256;
        out[(size_t)row * HID + col] = f2bf((v[i] - mu) * rstd * w[col] + b[col]);
    }
}

// ---------------- qkv pack: fp32 qkv (S,3,16,80) -> rotary + bf16 attention layouts
__global__ __launch_bounds__(256) void qkv_pack(const float* __restrict__ qkv,
                                                const float* __restrict__ rot,
                                                u16* __restrict__ Qp, u16* __restrict__ Kp,
                                                u16* __restrict__ Vt) {
    const float QSC = 0.111803398874989485f * LOG2E;
    int s0 = blockIdx.x * 64, h = blockIdx.y;
    int tid = threadIdx.x;
    __shared__ u16 vlds[80 * 66];
    for (int idx = tid; idx < 64 * 40; idx += 256) {
        int r = idx / 40, d = idx - r * 40;
        const float* base = qkv + (size_t)(s0 + r) * 3840 + h * 80;
        float sn, cs;
        __sincosf(rot[(size_t)(s0 + r) * 40 + d], &sn, &cs);
        float q1 = base[d], q2 = base[d + 40];
        float k1 = base[1280 + d], k2 = base[1280 + d + 40];
        size_t ro = ((size_t)h * SEQ + s0 + r) * 128;
        Qp[ro + d]      = f2bf((q1 * cs - q2 * sn) * QSC);
        Qp[ro + d + 40] = f2bf((q2 * cs + q1 * sn) * QSC);
        Kp[ro + d]      = f2bf(k1 * cs - k2 * sn);
        Kp[ro + d + 40] = f2bf(k2 * cs + k1 * sn);
    }
    for (int idx = tid; idx < 64 * 48; idx += 256) {
        int r = idx / 48, d = 80 + (idx - r * 48);
        size_t ro = ((size_t)h * SEQ + s0 + r) * 128;
        Qp[ro + d] = 0; Kp[ro + d] = 0;
    }
    for (int idx = tid; idx < 64 * 80; idx += 256) {
        int r = idx / 80, d = idx - r * 80;
        vlds[d * 66 + r] = f2bf(qkv[(size_t)(s0 + r) * 3840 + 2560 + h * 80 + d]);
    }
    __syncthreads();
    for (int idx = tid; idx < 80 * 64; idx += 256) {
        int d = idx >> 6, ky = idx & 63;
        Vt[((size_t)h * 80 + d) * SEQ + s0 + ky] = vlds[d * 66 + ky];
    }
}

// ---------------- GEMM v4b: BM x 128 tile, 8 waves (2M x 4N), BK=64,
// TRIPLE-buffered LDS, depth-2 prefetch, counted vmcnt (never 0 in steady state).
// Race-freedom: stage at tile t writes buffer (t+2)%3, whose last readers finished
// at the t-1 boundary barrier; one barrier per tile keeps waves within one tile.
// EPI 0: f32 out + bias (qkv)
// EPI 1: f32 out + bias + residual (proj, down)
// EPI 2: dual interleaved gate/up, silu fuse, bf16 out (mlp)
template<int BM, int EPI>
__global__ __launch_bounds__(512, 2) void gemm8(const u16* __restrict__ A,
                                                const u16* __restrict__ B,
                                                const float* __restrict__ bias0,
                                                const float* __restrict__ bias1,
                                                const float* __restrict__ res,
                                                float* __restrict__ outf,
                                                u16* __restrict__ outh,
                                                int N, int K) {
    constexpr int MT   = 3072 / BM;      // M tiles
    constexpr int MF   = BM / 32;        // m-frags per wave (per-wave M = BM/2)
    constexpr int LA   = BM / 64;        // A gld16 per thread per tile
    constexpr int LT   = LA + 2;         // total gld16 per thread per tile
    constexpr int ABUF = BM * 64;        // u16 per A tile
    constexpr int BUFU = ABUF + 8192;    // u16 per (A+B) buffer
    __shared__ u16 sbuf[3 * BUFU];

    int tid = threadIdx.x, lane = tid & 63, wave = tid >> 6;
    int quad = lane >> 4, r15 = lane & 15;
    int wm = wave >> 2, wn = wave & 3;   // 2 x 4 wave grid; per-wave out (BM/2) x 32

    // bijective XCD swizzle (m204)
    int nwg = gridDim.x;
    int q8 = nwg >> 3, r8 = nwg & 7;
    int xcd = blockIdx.x & 7, j = blockIdx.x >> 3;
    int wg = (xcd < r8 ? xcd * (q8 + 1) : r8 * (q8 + 1) + (xcd - r8) * q8) + j;
    int bx = wg / MT, by = wg % MT;
    int mBase = by * BM, nBase = bx * 128;

    // staging descriptors
    int rs = tid >> 3, cs = tid & 7;
    int c0 = cs ^ (rs & 7);
    const u16* gA = A + (size_t)(mBase + rs) * K + c0 * 8;
    const u16* gB = B + (size_t)(nBase + rs) * K + c0 * 8;
    int nK = K >> 6;

    f32x4 acc[MF][2] = {};

    // stage load j (of LT) for K-tile kt into buffer kt%3
    auto stage1 = [&](int kt, int jl) {
        int b = kt % 3;
        if (jl < LA) {
            gld16(gA + (size_t)kt * 64 + (size_t)(jl * 64) * K,
                  &sbuf[b * BUFU + jl * 4096 + wave * 512]);
        } else {
            int i = jl - LA;
            gld16(gB + (size_t)kt * 64 + (size_t)(i * 64) * K,
                  &sbuf[b * BUFU + ABUF + i * 4096 + wave * 512]);
        }
    };

    // prologue: fully stage tiles 0 and 1
#pragma unroll
    for (int jl = 0; jl < LT; jl++) stage1(0, jl);
#pragma unroll
    for (int jl = 0; jl < LT; jl++) stage1(1, jl);
    if constexpr (BM == 256) asm volatile("s_waitcnt vmcnt(6)" ::: "memory");
    else                     asm volatile("s_waitcnt vmcnt(4)" ::: "memory");
    __builtin_amdgcn_s_barrier();

    for (int kt = 0; kt < nK; kt++) {
        const u16* Ab = &sbuf[(kt % 3) * BUFU];
        const u16* Bb = Ab + ABUF;
        bool pre = (kt + 2 < nK);
#pragma unroll
        for (int ks = 0; ks < 2; ks++) {
            bf16x8 af[MF], bf[2];
#pragma unroll
            for (int mi = 0; mi < MF; mi++)
                af[mi] = frag8(Ab, wm * (BM / 2) + mi * 16 + r15, ks, quad);
#pragma unroll
            for (int ni = 0; ni < 2; ni++)
                bf[ni] = frag8(Bb, wn * 32 + ni * 16 + r15, ks, quad);
            if (pre) {
#pragma unroll
                for (int jl = 0; jl < LT / 2; jl++) stage1(kt + 2, ks * (LT / 2) + jl);
            }
            __builtin_amdgcn_s_barrier();
            __builtin_amdgcn_s_setprio(1);
#pragma unroll
            for (int mi = 0; mi < MF; mi++)
#pragma unroll
                for (int ni = 0; ni < 2; ni++)
                    acc[mi][ni] = __builtin_amdgcn_mfma_f32_16x16x32_bf16(
                        af[mi], bf[ni], acc[mi][ni], 0, 0, 0);
            __builtin_amdgcn_s_setprio(0);
            if (ks == 0) __builtin_amdgcn_s_barrier();
        }
        // boundary: ensure tile kt+1 landed; keep kt+2's LT loads in flight
        if (pre) {
            if constexpr (BM == 256) asm volatile("s_waitcnt vmcnt(6)" ::: "memory");
            else                     asm volatile("s_waitcnt vmcnt(4)" ::: "memory");
        } else if (kt + 1 < nK) {
            asm volatile("s_waitcnt vmcnt(0)" ::: "memory");
        }
        __builtin_amdgcn_s_barrier();
    }

    if constexpr (EPI == 2) {
        // interleaved dual: ni=0 gate frag, ni=1 up frag (same real cols)
        int col = (nBase >> 1) + wn * 16 + r15;
        float gb = bias0[col], ub = bias1[col];
#pragma unroll
        for (int mi = 0; mi < MF; mi++)
#pragma unroll
            for (int jj = 0; jj < 4; jj++) {
                int row = mBase + wm * (BM / 2) + mi * 16 + quad * 4 + jj;
                float g = acc[mi][0][jj] + gb;
                float u = acc[mi][1][jj] + ub;
                float sg = g / (1.f + __expf(-g));
                outh[(size_t)row * INTER + col] = f2bf(sg * u);
            }
    } else {
#pragma unroll
        for (int ni = 0; ni < 2; ni++) {
            int col = nBase + wn * 32 + ni * 16 + r15;
            float bv = bias0[col];
#pragma unroll
            for (int mi = 0; mi < MF; mi++)
#pragma unroll
                for (int jj = 0; jj < 4; jj++) {
                    int row = mBase + wm * (BM / 2) + mi * 16 + quad * 4 + jj;
                    float v = acc[mi][ni][jj] + bv;
                    if constexpr (EPI == 1) v += res[(size_t)row * N + col];
                    outf[(size_t)row * N + col] = v;
                }
        }
    }
}

// ---------------- flash attention with sinks, QR query rows per block
// QR=64: windowed (1 K-tile);  QR=128: full (SEQ/64 K-tiles, 2 m-frags/wave)
template<int QR>
__global__ __launch_bounds__(256) void attn_kernel(const u16* __restrict__ Qp,
                                                   const u16* __restrict__ Kp,
                                                   const u16* __restrict__ Vt,
                                                   const float* __restrict__ s_aux,
                                                   u16* __restrict__ out) {
    constexpr int MH = QR / 64;          // m-frags per wave (wave owns 16*MH rows)
    __shared__ u16 q_lds[QR * 128];
    __shared__ u16 k_lds[8192];
    __shared__ u16 v_lds[5120];
    __shared__ u16 p_lds[QR * 72];

    int qt = blockIdx.x, h = blockIdx.y;
    int tid = threadIdx.x, lane = tid & 63, wave = tid >> 6;
    int quad = lane >> 4, r15 = lane & 15;

    const u16* Qh = Qp + (size_t)h * SEQ * 128;
    const u16* Kh = Kp + (size_t)h * SEQ * 128;
    const u16* Vh = Vt + (size_t)h * 80 * SEQ;

    {
        int q0 = qt * QR;
#pragma unroll
        for (int i = 0; i < QR / 16; i++) {
            int slot = i * 256 + tid;
            int row = slot >> 4, cc = slot & 15;
            int c = cc ^ (row & 7);
            gld16(Qh + (size_t)(q0 + row) * 128 + c * 8, &q_lds[(i * 256 + wave * 64) * 8]);
        }
    }
    __syncthreads();
    bf16x8 aq[MH][3];
#pragma unroll
    for (int mh = 0; mh < MH; mh++)
#pragma unroll
        for (int ks = 0; ks < 3; ks++) {
            int row = wave * (16 * MH) + mh * 16 + r15;
            int c = ks * 4 + quad;
            aq[mh][ks] = *(const bf16x8*)&q_lds[(row * 16 + (c ^ (row & 7))) * 8];
        }

    float l_j[MH][4] = {};
    f32x4 ov[MH][5] = {};

    int nT = (QR == 64) ? 1 : (SEQ / 64);
    int tBase = (QR == 64) ? qt : 0;
    for (int t = 0; t < nT; t++) {
        int key0 = (tBase + t) * 64;
        __syncthreads();
#pragma unroll
        for (int i = 0; i < 4; i++) {
            int slot = i * 256 + wave * 64 + lane;
            int row = slot >> 4, cc = slot & 15;
            int c = cc ^ (row & 7);
            gld16(Kh + (size_t)(key0 + row) * 128 + c * 8, &k_lds[(i * 256 + wave * 64) * 8]);
        }
#pragma unroll
        for (int i = 0; i < 2; i++) {
            int slot = i * 256 + wave * 64 + lane;
            int row = slot >> 3, cc = slot & 7;
            int c = cc ^ (row & 7);
            gld16(Vh + (size_t)row * SEQ + key0 + c * 8, &v_lds[(i * 256 + wave * 64) * 8]);
        }
        if (wave < 2) {
            int slot = 512 + wave * 64 + lane;
            int row = slot >> 3, cc = slot & 7;
            int c = cc ^ (row & 7);
            gld16(Vh + (size_t)row * SEQ + key0 + c * 8, &v_lds[(512 + wave * 64) * 8]);
        }
        __syncthreads();

        f32x4 sc[MH][4] = {};
#pragma unroll
        for (int nt = 0; nt < 4; nt++)
#pragma unroll
            for (int ks = 0; ks < 3; ks++) {
                int row = nt * 16 + r15;
                int c = ks * 4 + quad;
                bf16x8 bk = *(const bf16x8*)&k_lds[(row * 16 + (c ^ (row & 7))) * 8];
#pragma unroll
                for (int mh = 0; mh < MH; mh++)
                    sc[mh][nt] = __builtin_amdgcn_mfma_f32_16x16x32_bf16(aq[mh][ks], bk, sc[mh][nt], 0, 0, 0);
            }
#pragma unroll
        for (int mh = 0; mh < MH; mh++)
#pragma unroll
            for (int nt = 0; nt < 4; nt++)
#pragma unroll
                for (int jj = 0; jj < 4; jj++) {
                    float p = __builtin_amdgcn_exp2f(sc[mh][nt][jj] - M2C);
                    l_j[mh][jj] += p;
                    p_lds[(wave * 16 * MH + mh * 16 + quad * 4 + jj) * 72 + nt * 16 + r15] = f2bf(p);
                }
        asm volatile("s_waitcnt lgkmcnt(0)" ::: "memory");
        bf16x8 ap[MH][2];
#pragma unroll
        for (int mh = 0; mh < MH; mh++)
#pragma unroll
            for (int ks = 0; ks < 2; ks++)
                ap[mh][ks] = *(const bf16x8*)&p_lds[(wave * 16 * MH + mh * 16 + r15) * 72 + ks * 32 + quad * 8];
#pragma unroll
        for (int t5 = 0; t5 < 5; t5++)
#pragma unroll
            for (int ks = 0; ks < 2; ks++) {
                int d = t5 * 16 + r15;
                int c = ks * 4 + quad;
                bf16x8 bv = *(const bf16x8*)&v_lds[(d * 8 + (c ^ (d & 7))) * 8];
#pragma unroll
                for (int mh = 0; mh < MH; mh++)
                    ov[mh][t5] = __builtin_amdgcn_mfma_f32_16x16x32_bf16(ap[mh][ks], bv, ov[mh][t5], 0, 0, 0);
            }
    }
#pragma unroll
    for (int mh = 0; mh < MH; mh++)
#pragma unroll
        for (int off = 1; off < 16; off <<= 1)
#pragma unroll
            for (int jj = 0; jj < 4; jj++)
                l_j[mh][jj] += __shfl_xor(l_j[mh][jj], off, 64);
    float sink = s_aux[h];
    float se = __builtin_amdgcn_exp2f(sink * LOG2E - M2C);
#pragma unroll
    for (int mh = 0; mh < MH; mh++)
#pragma unroll
        for (int jj = 0; jj < 4; jj++) l_j[mh][jj] = 1.f / (l_j[mh][jj] + se);
#pragma unroll
    for (int mh = 0; mh < MH; mh++)
#pragma unroll
        for (int t5 = 0; t5 < 5; t5++)
#pragma unroll
            for (int jj = 0; jj < 4; jj++) {
                int row = qt * QR + wave * 16 * MH + mh * 16 + quad * 4 + jj;
                int d = t5 * 16 + r15;
                out[(size_t)row * HID + h * 80 + d] = f2bf(ov[mh][t5][jj] * l_j[mh][jj]);
            }
}

__global__ __launch_bounds__(256) void copy4_kernel(const float4* __restrict__ src,
                                                    float4* __restrict__ dst) {
    size_t i = (size_t)blockIdx.x * 256 + threadIdx.x;
    dst[i] = src[i];
}

extern "C" void kernel_launch(void* const* d_in, const int* in_sizes, int n_in,
                              void* d_out, int out_size, void* d_ws, size_t ws_size,
                              hipStream_t stream) {
    const float* x      = (const float*)d_in[0];
    const float* rot    = (const float*)d_in[1];
    const float* s_aux  = (const float*)d_in[2];
    const float* ln1_w  = (const float*)d_in[3];
    const float* ln1_b  = (const float*)d_in[4];
    const float* qkv_w  = (const float*)d_in[5];
    const float* qkv_b  = (const float*)d_in[6];
    const float* proj_w = (const float*)d_in[7];
    const float* proj_b = (const float*)d_in[8];
    const float* ln2_w  = (const float*)d_in[9];
    const float* ln2_b  = (const float*)d_in[10];
    const float* gate_w = (const float*)d_in[11];
    const float* gate_b = (const float*)d_in[12];
    const float* up_w   = (const float*)d_in[13];
    const float* up_b   = (const float*)d_in[14];
    const float* down_w = (const float*)d_in[15];
    const float* down_b = (const float*)d_in[16];

    char* ws = (char*)d_ws;
    size_t off = 0;
    auto alloc = [&](size_t n) -> char* {
        char* p = ws + off; off += (n + 255) & ~(size_t)255; return p;
    };
    u16* wt_qkv  = (u16*)alloc((size_t)4 * 3840 * 1280 * 2);
    u16* wt_proj = (u16*)alloc((size_t)4 * 1280 * 1280 * 2);
    u16* wt_gu   = (u16*)alloc((size_t)4 * 9216 * 1280 * 2);   // interleaved gate/up
    u16* wt_down = (u16*)alloc((size_t)4 * 1280 * 4608 * 2);
    float* h     = (float*)alloc((size_t)3072 * 1280 * 4);
    u16*  xn     = (u16*)alloc((size_t)3072 * 1280 * 2);
    float* gbuf  = (float*)alloc((size_t)3072 * 4608 * 4);
    float* qkvb  = gbuf;  // alias: qkv buffer dead before MLP
    u16*  attnb  = (u16*)alloc((size_t)3072 * 1280 * 2);
    float* ubuf  = (float*)alloc((size_t)3072 * 4608 * 4);
    u16*  mbuf   = (u16*)alloc((size_t)3072 * 4608 * 2);
    u16* Qp  = (u16*)ubuf;
    u16* Kp  = Qp + (size_t)NHEADS * SEQ * 128;
    u16* Vtp = Kp + (size_t)NHEADS * SEQ * 128;

    transpose_pack<<<dim3(120, 40, 4), 256, 0, stream>>>(qkv_w,  wt_qkv,  1280, 3840);
    transpose_pack<<<dim3(40,  40, 4), 256, 0, stream>>>(proj_w, wt_proj, 1280, 1280);
    transpose_pack_gu<<<dim3(144, 40, 4), 256, 0, stream>>>(gate_w, wt_gu, 1280, 4608, 0);
    transpose_pack_gu<<<dim3(144, 40, 4), 256, 0, stream>>>(up_w,   wt_gu, 1280, 4608, 1);
    transpose_pack<<<dim3(40, 144, 4), 256, 0, stream>>>(down_w, wt_down, 4608, 1280);

    copy4_kernel<<<3840, 256, 0, stream>>>((const float4*)x, (float4*)h);

    for (int l = 0; l < 4; l++) {
        ln_kernel<<<3072, 256, 0, stream>>>(h, ln1_w + l * 1280, ln1_b + l * 1280, xn);
        gemm8<256, 0><<<360, 512, 0, stream>>>(xn, wt_qkv + (size_t)l * 3840 * 1280,
                                               qkv_b + l * 3840, nullptr, nullptr,
                                               qkvb, nullptr, 3840, 1280);
        qkv_pack<<<dim3(48, 16), 256, 0, stream>>>(qkvb, rot, Qp, Kp, Vtp);
        if (l == 3)
            attn_kernel<128><<<dim3(SEQ / 128, 16), 256, 0, stream>>>(Qp, Kp, Vtp, s_aux, attnb);
        else
            attn_kernel<64><<<dim3(SEQ / 64, 16), 256, 0, stream>>>(Qp, Kp, Vtp, s_aux, attnb);
        gemm8<128, 1><<<240, 512, 0, stream>>>(attnb, wt_proj + (size_t)l * 1280 * 1280,
                                               proj_b + l * 1280, nullptr, h,
                                               h, nullptr, 1280, 1280);
        ln_kernel<<<3072, 256, 0, stream>>>(h, ln2_w + l * 1280, ln2_b + l * 1280, xn);
        gemm8<256, 2><<<864, 512, 0, stream>>>(xn, wt_gu + (size_t)l * 9216 * 1280,
                                               gate_b + l * 4608, up_b + l * 4608, nullptr,
                                               nullptr, mbuf, 9216, 1280);
        float* outp = (l == 3) ? (float*)d_out : h;
        gemm8<128, 1><<<240, 512, 0, stream>>>(mbuf, wt_down + (size_t)l * 4608 * 1280,
                                               down_b + l * 1280, nullptr, h,
                                               outp, nullptr, 1280, 4608);
    }
}

// Round 4
// 1466.869 us; speedup vs baseline: 1.1940x; 1.0614x over previous
//
#include <hip/hip_runtime.h>
#include <math.h>

typedef unsigned short u16;
typedef unsigned int u32;

using bf16x8 = __attribute__((ext_vector_type(8))) __bf16;
using f32x4  = __attribute__((ext_vector_type(4))) float;

#define SEQ 3072
#define HID 1280
#define NHEADS 16
#define HDIM 80
#define INTER 4608

#define LOG2E 1.44269504088896f
#define M2C   11.5415603f   /* 8 * log2(e) */

__device__ __forceinline__ u16 f2bf(float f) {
    __bf16 h = (__bf16)f;               // HW v_cvt, RNE
    return __builtin_bit_cast(u16, h);
}

__device__ __forceinline__ void gld16(const void* g, void* l) {
    __builtin_amdgcn_global_load_lds((const __attribute__((address_space(1))) void*)g,
                                     (__attribute__((address_space(3))) void*)l,
                                     16, 0, 0);
}

// swizzled fragment read: row-major tiles of 8 u16 chunks, chunk c at slot c^(row&7)
__device__ __forceinline__ bf16x8 frag8(const u16* base, int row, int ks, int quad) {
    int c = ks * 4 + quad;
    return *(const bf16x8*)&base[(row * 8 + (c ^ (row & 7))) * 8];
}

// ---------------- transpose + bf16 pack:  W (L,K,N) f32  ->  Wt (L,N,K) bf16
__global__ __launch_bounds__(256) void transpose_pack(const float* __restrict__ src,
                                                      u16* __restrict__ dst, int K, int N) {
    __shared__ float tile[32][33];
    int l = blockIdx.z;
    const float* s = src + (size_t)l * K * N;
    u16* d = dst + (size_t)l * N * K;
    int n0 = blockIdx.x * 32, k0 = blockIdx.y * 32;
    int tx = threadIdx.x & 31, ty = threadIdx.x >> 5;
#pragma unroll
    for (int i = 0; i < 4; i++) {
        int k = ty + i * 8;
        tile[k][tx] = s[(size_t)(k0 + k) * N + n0 + tx];
    }
    __syncthreads();
#pragma unroll
    for (int i = 0; i < 4; i++) {
        int n = ty + i * 8;
        d[(size_t)(n0 + n) * K + k0 + tx] = f2bf(tile[tx][n]);
    }
}

// transpose+pack gate/up into a single interleaved buffer (L, 2N, K):
// real col g, which in {0:gate, 1:up} -> row n2 = ((g>>4)<<5) | (g&15) | (which<<4)
__global__ __launch_bounds__(256) void transpose_pack_gu(const float* __restrict__ src,
                                                         u16* __restrict__ dst, int K, int N,
                                                         int which) {
    __shared__ float tile[32][33];
    int l = blockIdx.z;
    const float* s = src + (size_t)l * K * N;
    u16* d = dst + (size_t)l * (2 * N) * K;
    int n0 = blockIdx.x * 32, k0 = blockIdx.y * 32;
    int tx = threadIdx.x & 31, ty = threadIdx.x >> 5;
#pragma unroll
    for (int i = 0; i < 4; i++) {
        int k = ty + i * 8;
        tile[k][tx] = s[(size_t)(k0 + k) * N + n0 + tx];
    }
    __syncthreads();
#pragma unroll
    for (int i = 0; i < 4; i++) {
        int n = ty + i * 8;
        int g = n0 + n;
        int n2 = ((g >> 4) << 5) | (g & 15) | (which << 4);
        d[(size_t)n2 * K + k0 + tx] = f2bf(tile[tx][n]);
    }
}

// ---------------- layernorm f32 -> bf16 (one row per block)
__global__ __launch_bounds__(256) void ln_kernel(const float* __restrict__ x,
                                                 const float* __restrict__ w,
                                                 const float* __restrict__ b,
                                                 u16* __restrict__ out) {
    int row = blockIdx.x;
    const float* xr = x + (size_t)row * HID;
    float v[5]; float s = 0.f, s2 = 0.f;
#pragma unroll
    for (int i = 0; i < 5; i++) { float t = xr[threadIdx.x + i * 256]; v[i] = t; s += t; s2 += t * t; }
#pragma unroll
    for (int off = 32; off > 0; off >>= 1) { s += __shfl_down(s, off); s2 += __shfl_down(s2, off); }
    __shared__ float red[8];
    int wv = threadIdx.x >> 6;
    if ((threadIdx.x & 63) == 0) { red[wv] = s; red[wv + 4] = s2; }
    __syncthreads();
    s  = red[0] + red[1] + red[2] + red[3];
    s2 = red[4] + red[5] + red[6] + red[7];
    float mu  = s * (1.f / HID);
    float var = s2 * (1.f / HID) - mu * mu;
    float rstd = rsqrtf(var + 1e-6f);
#pragma unroll
    for (int i = 0; i < 5; i++) {
        int col = threadIdx.x + i * 256;
        out[(size_t)row * HID + col] = f2bf((v[i] - mu) * rstd * w[col] + b[col]);
    }
}

// ---------------- qkv pack: fp32 qkv (S,3,16,80) -> rotary + bf16 attention layouts
__global__ __launch_bounds__(256) void qkv_pack(const float* __restrict__ qkv,
                                                const float* __restrict__ rot,
                                                u16* __restrict__ Qp, u16* __restrict__ Kp,
                                                u16* __restrict__ Vt) {
    const float QSC = 0.111803398874989485f * LOG2E;
    int s0 = blockIdx.x * 64, h = blockIdx.y;
    int tid = threadIdx.x;
    __shared__ u16 vlds[80 * 66];
    for (int idx = tid; idx < 64 * 40; idx += 256) {
        int r = idx / 40, d = idx - r * 40;
        const float* base = qkv + (size_t)(s0 + r) * 3840 + h * 80;
        float sn, cs;
        __sincosf(rot[(size_t)(s0 + r) * 40 + d], &sn, &cs);
        float q1 = base[d], q2 = base[d + 40];
        float k1 = base[1280 + d], k2 = base[1280 + d + 40];
        size_t ro = ((size_t)h * SEQ + s0 + r) * 128;
        Qp[ro + d]      = f2bf((q1 * cs - q2 * sn) * QSC);
        Qp[ro + d + 40] = f2bf((q2 * cs + q1 * sn) * QSC);
        Kp[ro + d]      = f2bf(k1 * cs - k2 * sn);
        Kp[ro + d + 40] = f2bf(k2 * cs + k1 * sn);
    }
    for (int idx = tid; idx < 64 * 48; idx += 256) {
        int r = idx / 48, d = 80 + (idx - r * 48);
        size_t ro = ((size_t)h * SEQ + s0 + r) * 128;
        Qp[ro + d] = 0; Kp[ro + d] = 0;
    }
    for (int idx = tid; idx < 64 * 80; idx += 256) {
        int r = idx / 80, d = idx - r * 80;
        vlds[d * 66 + r] = f2bf(qkv[(size_t)(s0 + r) * 3840 + 2560 + h * 80 + d]);
    }
    __syncthreads();
    for (int idx = tid; idx < 80 * 64; idx += 256) {
        int d = idx >> 6, ky = idx & 63;
        Vt[((size_t)h * 80 + d) * SEQ + s0 + ky] = vlds[d * 66 + ky];
    }
}

// ---------------- gemm256: 192x256 tile, 8 waves (2M x 4N), BK=64, per-wave 96x64.
// A double-buffered (2x24KB) + B triple-buffered (3x32KB) = 147456 B LDS (proven size).
// During tile t: ks=0 issues A(t+1) (3 loads), ks=1 issues B(t+2) (4 loads);
// boundary waits vmcnt(4) -> B(t+2) stays in flight, never drains in steady state.
// Race-freedom: A(t+1) targets buf (t+1)%2 last read by tile t-1 (done at its
// boundary barrier); B(t+2) targets (t+2)%3 = (t-1)%3, same argument.
// EPI 0: f32+bias (qkv). EPI 2: dual interleaved gate/up, silu fuse, bf16 out.
template<int EPI>
__global__ __launch_bounds__(512, 2) void gemm256(const u16* __restrict__ A,
                                                  const u16* __restrict__ B,
                                                  const float* __restrict__ bias0,
                                                  const float* __restrict__ bias1,
                                                  float* __restrict__ outf,
                                                  u16* __restrict__ outh,
                                                  int N, int K) {
    __shared__ u16 sbuf[73728];          // 147456 B: A 2x12288 u16, B 3x16384 u16
    int tid = threadIdx.x, lane = tid & 63, wave = tid >> 6;
    int quad = lane >> 4, r15 = lane & 15;
    int wm = wave >> 2, wn = wave & 3;   // 2M x 4N; per-wave out 96x64

    // bijective XCD swizzle (m204)
    int nwg = gridDim.x;
    int q8 = nwg >> 3, r8 = nwg & 7;
    int xcd = blockIdx.x & 7, j = blockIdx.x >> 3;
    int wg = (xcd < r8 ? xcd * (q8 + 1) : r8 * (q8 + 1) + (xcd - r8) * q8) + j;
    int bx = wg >> 4, by = wg & 15;      // M = 3072 -> 16 row tiles of 192
    int mBase = by * 192, nBase = bx * 256;

    int rs = tid >> 3, cs = tid & 7;
    int c0 = cs ^ (rs & 7);
    const u16* gA = A + (size_t)(mBase + rs) * K + c0 * 8;
    const u16* gB = B + (size_t)(nBase + rs) * K + c0 * 8;
    int nK = K >> 6;

    f32x4 acc[6][4] = {};

    auto stageA = [&](int kt, int jl) {      // jl 0..2, 64 rows each
        gld16(gA + (size_t)kt * 64 + (size_t)(jl * 64) * K,
              &sbuf[(kt & 1) * 12288 + jl * 4096 + wave * 512]);
    };
    auto stageB = [&](int kt, int jl) {      // jl 0..3
        gld16(gB + (size_t)kt * 64 + (size_t)(jl * 64) * K,
              &sbuf[24576 + (kt % 3) * 16384 + jl * 4096 + wave * 512]);
    };

    // prologue: A(0), B(0), B(1); wait oldest 7 (A0+B0), keep B(1) in flight
#pragma unroll
    for (int jl = 0; jl < 3; jl++) stageA(0, jl);
#pragma unroll
    for (int jl = 0; jl < 4; jl++) stageB(0, jl);
#pragma unroll
    for (int jl = 0; jl < 4; jl++) stageB(1, jl);
    asm volatile("s_waitcnt vmcnt(4)" ::: "memory");
    __builtin_amdgcn_s_barrier();

    for (int kt = 0; kt < nK; kt++) {
        const u16* Ab = &sbuf[(kt & 1) * 12288];
        const u16* Bb = &sbuf[24576 + (kt % 3) * 16384];
        bool preA = (kt + 1 < nK), preB = (kt + 2 < nK);
#pragma unroll
        for (int ks = 0; ks < 2; ks++) {
            bf16x8 af[6], bf[4];
#pragma unroll
            for (int mi = 0; mi < 6; mi++)
                af[mi] = frag8(Ab, wm * 96 + mi * 16 + r15, ks, quad);
#pragma unroll
            for (int ni = 0; ni < 4; ni++)
                bf[ni] = frag8(Bb, wn * 64 + ni * 16 + r15, ks, quad);
            if (ks == 0) {
                if (preA) { stageA(kt + 1, 0); stageA(kt + 1, 1); stageA(kt + 1, 2); }
            } else {
                if (preB) { stageB(kt + 2, 0); stageB(kt + 2, 1); stageB(kt + 2, 2); stageB(kt + 2, 3); }
            }
            __builtin_amdgcn_s_barrier();
            __builtin_amdgcn_s_setprio(1);
#pragma unroll
            for (int mi = 0; mi < 6; mi++)
#pragma unroll
                for (int ni = 0; ni < 4; ni++)
                    acc[mi][ni] = __builtin_amdgcn_mfma_f32_16x16x32_bf16(
                        af[mi], bf[ni], acc[mi][ni], 0, 0, 0);
            __builtin_amdgcn_s_setprio(0);
            if (ks == 0) __builtin_amdgcn_s_barrier();
        }
        if (preB)      { asm volatile("s_waitcnt vmcnt(4)" ::: "memory"); }
        else if (preA) { asm volatile("s_waitcnt vmcnt(0)" ::: "memory"); }
        __builtin_amdgcn_s_barrier();
    }

    if constexpr (EPI == 0) {
#pragma unroll
        for (int ni = 0; ni < 4; ni++) {
            int col = nBase + wn * 64 + ni * 16 + r15;
            float bv = bias0[col];
#pragma unroll
            for (int a = 0; a < 6; a++)
#pragma unroll
                for (int jj = 0; jj < 4; jj++) {
                    int row = mBase + wm * 96 + a * 16 + quad * 4 + jj;
                    outf[(size_t)row * N + col] = acc[a][ni][jj] + bv;
                }
        }
    } else {
        // interleaved dual: even ni = gate frag, odd ni = up frag (same real cols)
#pragma unroll
        for (int pp = 0; pp < 2; pp++) {
            int col = (nBase >> 1) + wn * 32 + pp * 16 + r15;
            float gb = bias0[col], ub = bias1[col];
#pragma unroll
            for (int a = 0; a < 6; a++)
#pragma unroll
                for (int jj = 0; jj < 4; jj++) {
                    int row = mBase + wm * 96 + a * 16 + quad * 4 + jj;
                    float g = acc[a][2 * pp][jj] + gb;
                    float u = acc[a][2 * pp + 1][jj] + ub;
                    float sg = g / (1.f + __expf(-g));
                    outh[(size_t)row * INTER + col] = f2bf(sg * u);
                }
        }
    }
}

// ---------------- GEMM v4b (proj / down): BM=128 x 128 tile, 8 waves, BK=64,
// triple-buffered, depth-2 prefetch, counted vmcnt.  EPI 1: f32 + bias + residual.
template<int BM, int EPI>
__global__ __launch_bounds__(512, 2) void gemm8(const u16* __restrict__ A,
                                                const u16* __restrict__ B,
                                                const float* __restrict__ bias0,
                                                const float* __restrict__ bias1,
                                                const float* __restrict__ res,
                                                float* __restrict__ outf,
                                                u16* __restrict__ outh,
                                                int N, int K) {
    constexpr int MT   = 3072 / BM;
    constexpr int MF   = BM / 32;
    constexpr int LA   = BM / 64;
    constexpr int LT   = LA + 2;
    constexpr int ABUF = BM * 64;
    constexpr int BUFU = ABUF + 8192;
    __shared__ u16 sbuf[3 * BUFU];

    int tid = threadIdx.x, lane = tid & 63, wave = tid >> 6;
    int quad = lane >> 4, r15 = lane & 15;
    int wm = wave >> 2, wn = wave & 3;

    int nwg = gridDim.x;
    int q8 = nwg >> 3, r8 = nwg & 7;
    int xcd = blockIdx.x & 7, j = blockIdx.x >> 3;
    int wg = (xcd < r8 ? xcd * (q8 + 1) : r8 * (q8 + 1) + (xcd - r8) * q8) + j;
    int bx = wg / MT, by = wg % MT;
    int mBase = by * BM, nBase = bx * 128;

    int rs = tid >> 3, cs = tid & 7;
    int c0 = cs ^ (rs & 7);
    const u16* gA = A + (size_t)(mBase + rs) * K + c0 * 8;
    const u16* gB = B + (size_t)(nBase + rs) * K + c0 * 8;
    int nK = K >> 6;

    f32x4 acc[MF][2] = {};

    auto stage1 = [&](int kt, int jl) {
        int b = kt % 3;
        if (jl < LA) {
            gld16(gA + (size_t)kt * 64 + (size_t)(jl * 64) * K,
                  &sbuf[b * BUFU + jl * 4096 + wave * 512]);
        } else {
            int i = jl - LA;
            gld16(gB + (size_t)kt * 64 + (size_t)(i * 64) * K,
                  &sbuf[b * BUFU + ABUF + i * 4096 + wave * 512]);
        }
    };

#pragma unroll
    for (int jl = 0; jl < LT; jl++) stage1(0, jl);
#pragma unroll
    for (int jl = 0; jl < LT; jl++) stage1(1, jl);
    asm volatile("s_waitcnt vmcnt(4)" ::: "memory");
    __builtin_amdgcn_s_barrier();

    for (int kt = 0; kt < nK; kt++) {
        const u16* Ab = &sbuf[(kt % 3) * BUFU];
        const u16* Bb = Ab + ABUF;
        bool pre = (kt + 2 < nK);
#pragma unroll
        for (int ks = 0; ks < 2; ks++) {
            bf16x8 af[MF], bf[2];
#pragma unroll
            for (int mi = 0; mi < MF; mi++)
                af[mi] = frag8(Ab, wm * (BM / 2) + mi * 16 + r15, ks, quad);
#pragma unroll
            for (int ni = 0; ni < 2; ni++)
                bf[ni] = frag8(Bb, wn * 32 + ni * 16 + r15, ks, quad);
            if (pre) {
#pragma unroll
                for (int jl = 0; jl < LT / 2; jl++) stage1(kt + 2, ks * (LT / 2) + jl);
            }
            __builtin_amdgcn_s_barrier();
            __builtin_amdgcn_s_setprio(1);
#pragma unroll
            for (int mi = 0; mi < MF; mi++)
#pragma unroll
                for (int ni = 0; ni < 2; ni++)
                    acc[mi][ni] = __builtin_amdgcn_mfma_f32_16x16x32_bf16(
                        af[mi], bf[ni], acc[mi][ni], 0, 0, 0);
            __builtin_amdgcn_s_setprio(0);
            if (ks == 0) __builtin_amdgcn_s_barrier();
        }
        if (pre) {
            asm volatile("s_waitcnt vmcnt(4)" ::: "memory");
        } else if (kt + 1 < nK) {
            asm volatile("s_waitcnt vmcnt(0)" ::: "memory");
        }
        __builtin_amdgcn_s_barrier();
    }

#pragma unroll
    for (int ni = 0; ni < 2; ni++) {
        int col = nBase + wn * 32 + ni * 16 + r15;
        float bv = bias0[col];
#pragma unroll
        for (int mi = 0; mi < MF; mi++)
#pragma unroll
            for (int jj = 0; jj < 4; jj++) {
                int row = mBase + wm * (BM / 2) + mi * 16 + quad * 4 + jj;
                float v = acc[mi][ni][jj] + bv;
                if constexpr (EPI == 1) v += res[(size_t)row * N + col];
                outf[(size_t)row * N + col] = v;
            }
    }
}

// ---------------- flash attention with sinks, QR query rows per block
template<int QR>
__global__ __launch_bounds__(256) void attn_kernel(const u16* __restrict__ Qp,
                                                   const u16* __restrict__ Kp,
                                                   const u16* __restrict__ Vt,
                                                   const float* __restrict__ s_aux,
                                                   u16* __restrict__ out) {
    constexpr int MH = QR / 64;
    __shared__ u16 q_lds[QR * 128];
    __shared__ u16 k_lds[8192];
    __shared__ u16 v_lds[5120];
    __shared__ u16 p_lds[QR * 72];

    int qt = blockIdx.x, h = blockIdx.y;
    int tid = threadIdx.x, lane = tid & 63, wave = tid >> 6;
    int quad = lane >> 4, r15 = lane & 15;

    const u16* Qh = Qp + (size_t)h * SEQ * 128;
    const u16* Kh = Kp + (size_t)h * SEQ * 128;
    const u16* Vh = Vt + (size_t)h * 80 * SEQ;

    {
        int q0 = qt * QR;
#pragma unroll
        for (int i = 0; i < QR / 16; i++) {
            int slot = i * 256 + tid;
            int row = slot >> 4, cc = slot & 15;
            int c = cc ^ (row & 7);
            gld16(Qh + (size_t)(q0 + row) * 128 + c * 8, &q_lds[(i * 256 + wave * 64) * 8]);
        }
    }
    __syncthreads();
    bf16x8 aq[MH][3];
#pragma unroll
    for (int mh = 0; mh < MH; mh++)
#pragma unroll
        for (int ks = 0; ks < 3; ks++) {
            int row = wave * (16 * MH) + mh * 16 + r15;
            int c = ks * 4 + quad;
            aq[mh][ks] = *(const bf16x8*)&q_lds[(row * 16 + (c ^ (row & 7))) * 8];
        }

    float l_j[MH][4] = {};
    f32x4 ov[MH][5] = {};

    int nT = (QR == 64) ? 1 : (SEQ / 64);
    int tBase = (QR == 64) ? qt : 0;
    for (int t = 0; t < nT; t++) {
        int key0 = (tBase + t) * 64;
        __syncthreads();
#pragma unroll
        for (int i = 0; i < 4; i++) {
            int slot = i * 256 + wave * 64 + lane;
            int row = slot >> 4, cc = slot & 15;
            int c = cc ^ (row & 7);
            gld16(Kh + (size_t)(key0 + row) * 128 + c * 8, &k_lds[(i * 256 + wave * 64) * 8]);
        }
#pragma unroll
        for (int i = 0; i < 2; i++) {
            int slot = i * 256 + wave * 64 + lane;
            int row = slot >> 3, cc = slot & 7;
            int c = cc ^ (row & 7);
            gld16(Vh + (size_t)row * SEQ + key0 + c * 8, &v_lds[(i * 256 + wave * 64) * 8]);
        }
        if (wave < 2) {
            int slot = 512 + wave * 64 + lane;
            int row = slot >> 3, cc = slot & 7;
            int c = cc ^ (row & 7);
            gld16(Vh + (size_t)row * SEQ + key0 + c * 8, &v_lds[(512 + wave * 64) * 8]);
        }
        __syncthreads();

        f32x4 sc[MH][4] = {};
#pragma unroll
        for (int nt = 0; nt < 4; nt++)
#pragma unroll
            for (int ks = 0; ks < 3; ks++) {
                int row = nt * 16 + r15;
                int c = ks * 4 + quad;
                bf16x8 bk = *(const bf16x8*)&k_lds[(row * 16 + (c ^ (row & 7))) * 8];
#pragma unroll
                for (int mh = 0; mh < MH; mh++)
                    sc[mh][nt] = __builtin_amdgcn_mfma_f32_16x16x32_bf16(aq[mh][ks], bk, sc[mh][nt], 0, 0, 0);
            }
#pragma unroll
        for (int mh = 0; mh < MH; mh++)
#pragma unroll
            for (int nt = 0; nt < 4; nt++)
#pragma unroll
                for (int jj = 0; jj < 4; jj++) {
                    float p = __builtin_amdgcn_exp2f(sc[mh][nt][jj] - M2C);
                    l_j[mh][jj] += p;
                    p_lds[(wave * 16 * MH + mh * 16 + quad * 4 + jj) * 72 + nt * 16 + r15] = f2bf(p);
                }
        asm volatile("s_waitcnt lgkmcnt(0)" ::: "memory");
        bf16x8 ap[MH][2];
#pragma unroll
        for (int mh = 0; mh < MH; mh++)
#pragma unroll
            for (int ks = 0; ks < 2; ks++)
                ap[mh][ks] = *(const bf16x8*)&p_lds[(wave * 16 * MH + mh * 16 + r15) * 72 + ks * 32 + quad * 8];
#pragma unroll
        for (int t5 = 0; t5 < 5; t5++)
#pragma unroll
            for (int ks = 0; ks < 2; ks++) {
                int d = t5 * 16 + r15;
                int c = ks * 4 + quad;
                bf16x8 bv = *(const bf16x8*)&v_lds[(d * 8 + (c ^ (d & 7))) * 8];
#pragma unroll
                for (int mh = 0; mh < MH; mh++)
                    ov[mh][t5] = __builtin_amdgcn_mfma_f32_16x16x32_bf16(ap[mh][ks], bv, ov[mh][t5], 0, 0, 0);
            }
    }
#pragma unroll
    for (int mh = 0; mh < MH; mh++)
#pragma unroll
        for (int off = 1; off < 16; off <<= 1)
#pragma unroll
            for (int jj = 0; jj < 4; jj++)
                l_j[mh][jj] += __shfl_xor(l_j[mh][jj], off, 64);
    float sink = s_aux[h];
    float se = __builtin_amdgcn_exp2f(sink * LOG2E - M2C);
#pragma unroll
    for (int mh = 0; mh < MH; mh++)
#pragma unroll
        for (int jj = 0; jj < 4; jj++) l_j[mh][jj] = 1.f / (l_j[mh][jj] + se);
#pragma unroll
    for (int mh = 0; mh < MH; mh++)
#pragma unroll
        for (int t5 = 0; t5 < 5; t5++)
#pragma unroll
            for (int jj = 0; jj < 4; jj++) {
                int row = qt * QR + wave * 16 * MH + mh * 16 + quad * 4 + jj;
                int d = t5 * 16 + r15;
                out[(size_t)row * HID + h * 80 + d] = f2bf(ov[mh][t5][jj] * l_j[mh][jj]);
            }
}

__global__ __launch_bounds__(256) void copy4_kernel(const float4* __restrict__ src,
                                                    float4* __restrict__ dst) {
    size_t i = (size_t)blockIdx.x * 256 + threadIdx.x;
    dst[i] = src[i];
}

extern "C" void kernel_launch(void* const* d_in, const int* in_sizes, int n_in,
                              void* d_out, int out_size, void* d_ws, size_t ws_size,
                              hipStream_t stream) {
    const float* x      = (const float*)d_in[0];
    const float* rot    = (const float*)d_in[1];
    const float* s_aux  = (const float*)d_in[2];
    const float* ln1_w  = (const float*)d_in[3];
    const float* ln1_b  = (const float*)d_in[4];
    const float* qkv_w  = (const float*)d_in[5];
    const float* qkv_b  = (const float*)d_in[6];
    const float* proj_w = (const float*)d_in[7];
    const float* proj_b = (const float*)d_in[8];
    const float* ln2_w  = (const float*)d_in[9];
    const float* ln2_b  = (const float*)d_in[10];
    const float* gate_w = (const float*)d_in[11];
    const float* gate_b = (const float*)d_in[12];
    const float* up_w   = (const float*)d_in[13];
    const float* up_b   = (const float*)d_in[14];
    const float* down_w = (const float*)d_in[15];
    const float* down_b = (const float*)d_in[16];

    char* ws = (char*)d_ws;
    size_t off = 0;
    auto alloc = [&](size_t n) -> char* {
        char* p = ws + off; off += (n + 255) & ~(size_t)255; return p;
    };
    u16* wt_qkv  = (u16*)alloc((size_t)4 * 3840 * 1280 * 2);
    u16* wt_proj = (u16*)alloc((size_t)4 * 1280 * 1280 * 2);
    u16* wt_gu   = (u16*)alloc((size_t)4 * 9216 * 1280 * 2);   // interleaved gate/up
    u16* wt_down = (u16*)alloc((size_t)4 * 1280 * 4608 * 2);
    float* h     = (float*)alloc((size_t)3072 * 1280 * 4);
    u16*  xn     = (u16*)alloc((size_t)3072 * 1280 * 2);
    float* gbuf  = (float*)alloc((size_t)3072 * 4608 * 4);
    float* qkvb  = gbuf;  // alias: qkv buffer dead before MLP
    u16*  attnb  = (u16*)alloc((size_t)3072 * 1280 * 2);
    float* ubuf  = (float*)alloc((size_t)3072 * 4608 * 4);
    u16*  mbuf   = (u16*)alloc((size_t)3072 * 4608 * 2);
    u16* Qp  = (u16*)ubuf;
    u16* Kp  = Qp + (size_t)NHEADS * SEQ * 128;
    u16* Vtp = Kp + (size_t)NHEADS * SEQ * 128;

    transpose_pack<<<dim3(120, 40, 4), 256, 0, stream>>>(qkv_w,  wt_qkv,  1280, 3840);
    transpose_pack<<<dim3(40,  40, 4), 256, 0, stream>>>(proj_w, wt_proj, 1280, 1280);
    transpose_pack_gu<<<dim3(144, 40, 4), 256, 0, stream>>>(gate_w, wt_gu, 1280, 4608, 0);
    transpose_pack_gu<<<dim3(144, 40, 4), 256, 0, stream>>>(up_w,   wt_gu, 1280, 4608, 1);
    transpose_pack<<<dim3(40, 144, 4), 256, 0, stream>>>(down_w, wt_down, 4608, 1280);

    copy4_kernel<<<3840, 256, 0, stream>>>((const float4*)x, (float4*)h);

    for (int l = 0; l < 4; l++) {
        ln_kernel<<<3072, 256, 0, stream>>>(h, ln1_w + l * 1280, ln1_b + l * 1280, xn);
        gemm256<0><<<240, 512, 0, stream>>>(xn, wt_qkv + (size_t)l * 3840 * 1280,
                                            qkv_b + l * 3840, nullptr,
                                            qkvb, nullptr, 3840, 1280);
        qkv_pack<<<dim3(48, 16), 256, 0, stream>>>(qkvb, rot, Qp, Kp, Vtp);
        if (l == 3)
            attn_kernel<128><<<dim3(SEQ / 128, 16), 256, 0, stream>>>(Qp, Kp, Vtp, s_aux, attnb);
        else
            attn_kernel<64><<<dim3(SEQ / 64, 16), 256, 0, stream>>>(Qp, Kp, Vtp, s_aux, attnb);
        gemm8<128, 1><<<240, 512, 0, stream>>>(attnb, wt_proj + (size_t)l * 1280 * 1280,
                                               proj_b + l * 1280, nullptr, h,
                                               h, nullptr, 1280, 1280);
        ln_kernel<<<3072, 256, 0, stream>>>(h, ln2_w + l * 1280, ln2_b + l * 1280, xn);
        gemm256<2><<<576, 512, 0, stream>>>(xn, wt_gu + (size_t)l * 9216 * 1280,
                                            gate_b + l * 4608, up_b + l * 4608,
                                            nullptr, mbuf, 9216, 1280);
        float* outp = (l == 3) ? (float*)d_out : h;
        gemm8<128, 1><<<240, 512, 0, stream>>>(mbuf, wt_down + (size_t)l * 4608 * 1280,
                                               down_b + l * 1280, nullptr, h,
                                               outp, nullptr, 1280, 4608);
    }
}